// Round 10
// baseline (309.791 us; speedup 1.0000x reference)
//
#include <hip/hip_runtime.h>
#include <math.h>

#define NB 8
#define NC 256
#define ND 32
#define NN 4096
#define NM 320                 // fused rows: 32 q + 32 k + 256 v
#define LOG2E 1.44269504088896f
#define XSTR 264               // proj LDS row stride (shorts), 16B-aligned rows

typedef short short8 __attribute__((ext_vector_type(8)));
typedef short short4v __attribute__((ext_vector_type(4)));
typedef float f32x4 __attribute__((ext_vector_type(4)));

__device__ __forceinline__ unsigned int f2bf_u(float f) {
    return (__float_as_uint(f) + 0x8000u) >> 16;
}
__device__ __forceinline__ unsigned short f2bf(float f) {
    return (unsigned short)f2bf_u(f);
}

// ---------------------------------------------------------------------------
// Repack fused weights [320x256] -> bf16 fragments.  Rows 0..31 = Wq*LOG2E,
// 32..63 = Wk, 64..319 = Wv.  Also bias[320].
// ---------------------------------------------------------------------------
__global__ __launch_bounds__(256) void repack_kernel(
    const float* __restrict__ Wq, const float* __restrict__ bq,
    const float* __restrict__ Wk, const float* __restrict__ bk,
    const float* __restrict__ Wv, const float* __restrict__ bv,
    unsigned short* __restrict__ wp, float* __restrict__ bias)
{
    const int T    = blockIdx.x * 256 + threadIdx.x;   // 81920 threads
    const int j    = T & 7;
    const int lane = (T >> 3) & 63;
    const int ks   = (T >> 9) & 7;
    const int mt   = T >> 12;
    const int m = mt * 16 + (lane & 15);
    const int k = ks * 32 + ((lane >> 4) << 3) + j;
    float wv;
    if (m < 32)       wv = Wq[m * NC + k] * LOG2E;
    else if (m < 64)  wv = Wk[(m - 32) * NC + k];
    else              wv = Wv[(m - 64) * NC + k];
    wp[T] = f2bf(wv);
    if (T < NM) {
        float bb;
        if (T < 32)      bb = bq[T] * LOG2E;
        else if (T < 64) bb = bk[T - 32];
        else             bb = bv[T - 64];
        bias[T] = bb;
    }
}

// ---------------------------------------------------------------------------
// MFMA projection.  A = x (m = pixel), B = W^T.  K and V outputs written in
// MFMA-FRAGMENT-LINEAR layout (one contiguous 512B/1KB transaction per frag):
//   K: [b][jtile(256)][lane(64)][8]  lane = (d>>3)*16 + (j&15), elem d&7
//   V: [b][ctile(16)][jtile(256)][lane(64)][4] lane = ((j>>2)&3)*16 + (c&15)
// ---------------------------------------------------------------------------
__global__ __launch_bounds__(256, 4) void proj_kernel(
    const float* __restrict__ x,
    const unsigned short* __restrict__ wp,
    const float* __restrict__ bias,
    unsigned short* __restrict__ q_ws,
    unsigned short* __restrict__ k_ws,
    unsigned short* __restrict__ v_ws)
{
    __shared__ __align__(16) unsigned short xs[32 * XSTR];   // 16.9 KB

    const int b  = blockIdx.x >> 7;          // 128 tiles per batch
    const int n0 = (blockIdx.x & 127) << 5;
    const int t  = threadIdx.x;

    {
        const int n  = t & 31;
        const int cg = t >> 5;               // 0..7
        const float* xb = x + (size_t)b * NC * NN + n0 + n;
        #pragma unroll
        for (int it = 0; it < 8; ++it) {
            const int c = 32 * it + 4 * cg;
            const float x0 = xb[(size_t)(c + 0) * NN];
            const float x1 = xb[(size_t)(c + 1) * NN];
            const float x2 = xb[(size_t)(c + 2) * NN];
            const float x3 = xb[(size_t)(c + 3) * NN];
            uint2 pk;
            pk.x = (f2bf_u(x1) << 16) | f2bf_u(x0);
            pk.y = (f2bf_u(x3) << 16) | f2bf_u(x2);
            *(uint2*)(xs + n * XSTR + c) = pk;
        }
    }
    __syncthreads();

    const int w    = t >> 6;
    const int lane = t & 63;
    const int li = lane & 15;
    const int qd = lane >> 4;

    f32x4 acc[5][2];
    #pragma unroll
    for (int u = 0; u < 5; ++u) {
        const float bb = bias[(w + 4 * u) * 16 + li];
        acc[u][0] = (f32x4){bb, bb, bb, bb};
        acc[u][1] = (f32x4){bb, bb, bb, bb};
    }

    #pragma unroll
    for (int ks = 0; ks < 8; ++ks) {
        short8 af[2];
        #pragma unroll
        for (int mt = 0; mt < 2; ++mt)
            af[mt] = *(const short8*)(xs + (mt * 16 + li) * XSTR + ks * 32 + qd * 8);
        #pragma unroll
        for (int u = 0; u < 5; ++u) {
            const int ct = w + 4 * u;
            const short8 bf = *(const short8*)(wp + (size_t)((ct * 8 + ks) * 64 + lane) * 8);
            acc[u][0] = __builtin_amdgcn_mfma_f32_16x16x32_bf16(af[0], bf, acc[u][0], 0, 0, 0);
            acc[u][1] = __builtin_amdgcn_mfma_f32_16x16x32_bf16(af[1], bf, acc[u][1], 0, 0, 0);
        }
    }

    #pragma unroll
    for (int u = 0; u < 5; ++u) {
        const int ct = w + 4 * u;
        if (ct < 2) {
            // Q: row-major [b][n][d] (read once by attn; layout uncritical)
            const int d = ct * 16 + li;
            #pragma unroll
            for (int mt = 0; mt < 2; ++mt)
                #pragma unroll
                for (int r = 0; r < 4; ++r) {
                    const int n = n0 + mt * 16 + 4 * qd + r;
                    q_ws[((size_t)b * NN + n) * ND + d] = f2bf(acc[u][mt][r]);
                }
        } else if (ct < 4) {
            // K: fragment-linear
            const int d = (ct & 1) * 16 + li;
            #pragma unroll
            for (int mt = 0; mt < 2; ++mt)
                #pragma unroll
                for (int r = 0; r < 4; ++r) {
                    const int n = n0 + mt * 16 + 4 * qd + r;
                    k_ws[((size_t)(b * 256 + (n >> 4)) * 64 + (d >> 3) * 16 + (n & 15)) * 8 + (d & 7)]
                        = f2bf(acc[u][mt][r]);
                }
        } else {
            // V: fragment-linear; uint2 = V[cv][n..n+3] -> lane (qd*16+li), 4 elems
            const int ctv = ct - 4;              // V c-tile 0..15
            #pragma unroll
            for (int mt = 0; mt < 2; ++mt) {
                const int jt = (n0 >> 4) + mt;
                uint2 pk;
                pk.x = (f2bf_u(acc[u][mt][1]) << 16) | f2bf_u(acc[u][mt][0]);
                pk.y = (f2bf_u(acc[u][mt][3]) << 16) | f2bf_u(acc[u][mt][2]);
                *(uint2*)(v_ws + (((size_t)(b * 16 + ctv) * 256 + jt) * 64 + qd * 16 + li) * 4) = pk;
            }
        }
    }
}

// ---------------------------------------------------------------------------
// Flash attention R17: R13's 2x-redundancy wave split (strip-pair sp=w&1,
// channel-half ch=w>>1) + FULL-HALF-LOOKAHEAD V slot pipeline.
//
// Ledger: R12 (4 waves x 64ch, 4x exp2 redundancy) = 155us, VALU-busy 87us
// (the floor of that family).  R13 (this split) cut VALU-busy to 50us
// (-43%, the theory worked) but stalled: its ct4..7 V loads were issued at
// top-of-half with only the halved S-phase (~250cyc) as cover vs 200-400cyc
// L2 latency -> MfmaUtil collapsed to 28%.  R16 showed more waves don't
// help (fixed costs scale).  R17 keeps R13's work split and restores the
// cover: ALL 8 V slots are reloaded for half h+1 inside PV(h), each right
// after its last use -> every V load has (rest of PV + full S-phase)
// >= ~500cyc of cover, uniform — the same scheme that made R12's loads
// latency-clean.  Prologue preloads all 8 slots for half 0.
// Tail prefetches read harmlessly into adjacent d_ws regions (never
// consumed; l_loc untouched — R12/R13 pattern, both passed).
// Fragment math identical to R12/R13 (passed): S = mfma_16x16x32(K,Q)
// leaves lane (li,qd) with S[i=li][j=16jt+4qd+r]; exp2+pack is exactly the
// B-fragment of v_mfma_f32_16x16x16bf16_1k, so P never leaves the lane.
// ---------------------------------------------------------------------------
__global__ __launch_bounds__(256, 2) void attn_kernel(
    const unsigned short* __restrict__ q_ws,
    const unsigned short* __restrict__ k_ws,
    const unsigned short* __restrict__ v_ws,
    float* __restrict__ out)
{
    const int b  = blockIdx.x & 7;           // batch == XCD
    const int i0 = (blockIdx.x >> 3) * 64;
    const int w    = threadIdx.x >> 6;       // 0..3
    const int lane = threadIdx.x & 63;
    const int li = lane & 15;
    const int qd = lane >> 4;
    const int sp = w & 1;                    // strip pair: i rows i0+32*sp..+31
    const int ch = w >> 1;                   // channel half: c0 = 128*ch
    const int c0 = 128 * ch;

    // Q fragments for this wave's 2 i-strips (B-operand of S-MFMA)
    short8 qf[2];
    #pragma unroll
    for (int sb = 0; sb < 2; ++sb)
        qf[sb] = *(const short8*)(q_ws + ((size_t)b * NN + i0 + 32 * sp + 16 * sb + li) * ND + qd * 8);

    // Fragment-linear bases: K frag = 512 shorts, V frag = 256 shorts
    const unsigned short* kfb = k_ws + ((size_t)b * 256 * 64 + lane) * 8;
    const unsigned short* vtb[8];
    #pragma unroll
    for (int ct = 0; ct < 8; ++ct)
        vtb[ct] = v_ws + (((size_t)(b * 16 + (c0 >> 4) + ct) * 256) * 64 + lane) * 4;

    f32x4 o[2][8];                           // [i-strip][c-tile] (acc regs)
    #pragma unroll
    for (int sb = 0; sb < 2; ++sb)
        #pragma unroll
        for (int ct = 0; ct < 8; ++ct)
            o[sb][ct] = (f32x4){0.f, 0.f, 0.f, 0.f};
    float l_loc[2] = {0.f, 0.f};
    const f32x4 z4 = {0.f, 0.f, 0.f, 0.f};

    short8 kHA[2], kHB[2];                   // K frags, half-chunk, dbl-buf
    uint2  vs[8][2];                         // V slots: [ct][jt], 1-half lookahead
    uint2  pk[2][2];                         // packed P: [sb][jt]

    // One 32-j half-chunk at j0 (frag f0 = j0/16); kc current, kn next.
    // vs[] holds THIS half's V on entry; every slot is reloaded for h+1.
    auto HALF = [&](int j0, short8 (&kc)[2], short8 (&kn)[2]) {
        const size_t f0 = (size_t)(j0 >> 4);
        // next-half K at TOP (double-buffered, no WAR): full-half cover
        kn[0] = *(const short8*)(kfb + (f0 + 2) * 512);
        kn[1] = *(const short8*)(kfb + (f0 + 3) * 512);
        // S phase: 4 MFMA + 16 exp2 + pack (this wave's 2 strips only)
        #pragma unroll
        for (int sb = 0; sb < 2; ++sb)
            #pragma unroll
            for (int jt = 0; jt < 2; ++jt) {
                const f32x4 s = __builtin_amdgcn_mfma_f32_16x16x32_bf16(kc[jt], qf[sb], z4, 0, 0, 0);
                const float p0 = __builtin_amdgcn_exp2f(s[0]);
                const float p1 = __builtin_amdgcn_exp2f(s[1]);
                const float p2 = __builtin_amdgcn_exp2f(s[2]);
                const float p3 = __builtin_amdgcn_exp2f(s[3]);
                l_loc[sb] += (p0 + p1) + (p2 + p3);
                const unsigned u0 = __float_as_uint(p0) + 0x8000u;
                const unsigned u1 = __float_as_uint(p1) + 0x8000u;
                const unsigned u2 = __float_as_uint(p2) + 0x8000u;
                const unsigned u3 = __float_as_uint(p3) + 0x8000u;
                pk[sb][jt].x = __builtin_amdgcn_perm(u1, u0, 0x07060302u);
                pk[sb][jt].y = __builtin_amdgcn_perm(u3, u2, 0x07060302u);
            }
        // PV phase: 8 ct-groups of 4 MFMA; EVERY slot reloaded for h+1
        // right after its last use (cover = rest of PV + next S-phase).
        #pragma unroll
        for (int ct = 0; ct < 8; ++ct) {
            #pragma unroll
            for (int sb = 0; sb < 2; ++sb)
                #pragma unroll
                for (int jt = 0; jt < 2; ++jt)
                    o[sb][ct] = __builtin_amdgcn_mfma_f32_16x16x16bf16_1k(
                        __builtin_bit_cast(short4v, vs[ct][jt]),
                        __builtin_bit_cast(short4v, pk[sb][jt]), o[sb][ct], 0, 0, 0);
            vs[ct][0] = *(const uint2*)(vtb[ct] + (f0 + 2) * 256);
            vs[ct][1] = *(const uint2*)(vtb[ct] + (f0 + 3) * 256);
        }
    };

    // ---- prologue: K(half 0), K(half 1) staged via kn path; V all 8 slots
    //      for half 0 ----
    kHA[0] = *(const short8*)(kfb);
    kHA[1] = *(const short8*)(kfb + 512);
    #pragma unroll
    for (int ct = 0; ct < 8; ++ct) {
        vs[ct][0] = *(const uint2*)(vtb[ct]);
        vs[ct][1] = *(const uint2*)(vtb[ct] + 256);
    }

    // ---- main loop: 64 iterations x 2 half-chunks.  Tail prefetches read
    // harmlessly into adjacent d_ws regions; never consumed. ----
    #pragma unroll 1
    for (int t = 0; t < 64; ++t) {
        HALF(64 * t,      kHA, kHB);
        HALF(64 * t + 32, kHB, kHA);
    }

    // ---- l reduction: fully intra-wave (sum over qd groups) ----
    #pragma unroll
    for (int sb = 0; sb < 2; ++sb) {
        l_loc[sb] += __shfl_xor(l_loc[sb], 16, 64);
        l_loc[sb] += __shfl_xor(l_loc[sb], 32, 64);
    }

    #pragma unroll
    for (int sb = 0; sb < 2; ++sb) {
        const float linv = 1.0f / l_loc[sb];
        #pragma unroll
        for (int ct = 0; ct < 8; ++ct) {
            const int c = c0 + ct * 16 + qd * 4;
            float* op = out + ((size_t)b * NC + c) * NN + i0 + 32 * sp + 16 * sb + li;
            #pragma unroll
            for (int r = 0; r < 4; ++r)
                op[(size_t)r * NN] = o[sb][ct][r] * linv;
        }
    }
}

// ---------------------------------------------------------------------------
extern "C" void kernel_launch(void* const* d_in, const int* in_sizes, int n_in,
                              void* d_out, int out_size, void* d_ws, size_t ws_size,
                              hipStream_t stream) {
    const float* x  = (const float*)d_in[0];
    const float* Wq = (const float*)d_in[1];
    const float* bq = (const float*)d_in[2];
    const float* Wk = (const float*)d_in[3];
    const float* bk = (const float*)d_in[4];
    const float* Wv = (const float*)d_in[5];
    const float* bv = (const float*)d_in[6];
    float* out = (float*)d_out;

    unsigned short* q_ws = (unsigned short*)d_ws;            // 2 MB
    unsigned short* k_ws = q_ws + (size_t)NB * NN * ND;      // 2 MB
    unsigned short* v_ws = k_ws + (size_t)NB * NN * ND;      // 16 MB
    unsigned short* wp   = v_ws + (size_t)NB * NC * NN;      // 160 KB
    float*          bias = (float*)(wp + (size_t)NM * NC);   // 1.25 KB

    repack_kernel<<<NM * NC / 256, 256, 0, stream>>>(Wq, bq, Wk, bk, Wv, bv, wp, bias);
    proj_kernel<<<NB * (NN / 32), 256, 0, stream>>>(x, wp, bias, q_ws, k_ws, v_ws);
    attn_kernel<<<NB * (NN / 64), 256, 0, stream>>>(q_ws, k_ws, v_ws, out);
}

// Round 13
// 227.567 us; speedup vs baseline: 1.3613x; 1.3613x over previous
//
#include <hip/hip_runtime.h>
#include <math.h>

#define NB 8
#define NC 256
#define ND 32
#define NN 4096
#define NM 320                 // fused rows: 32 q + 32 k + 256 v
#define LOG2E 1.44269504088896f
#define XSTR 264               // proj LDS row stride (shorts), 16B-aligned rows

typedef short short8 __attribute__((ext_vector_type(8)));
typedef short short4v __attribute__((ext_vector_type(4)));
typedef float f32x4 __attribute__((ext_vector_type(4)));

__device__ __forceinline__ unsigned int f2bf_u(float f) {
    return (__float_as_uint(f) + 0x8000u) >> 16;
}
__device__ __forceinline__ unsigned short f2bf(float f) {
    return (unsigned short)f2bf_u(f);
}

// ---------------------------------------------------------------------------
// Repack fused weights [320x256] -> bf16 fragments.  Rows 0..31 = Wq*LOG2E,
// 32..63 = Wk, 64..319 = Wv.  Also bias[320].
// ---------------------------------------------------------------------------
__global__ __launch_bounds__(256) void repack_kernel(
    const float* __restrict__ Wq, const float* __restrict__ bq,
    const float* __restrict__ Wk, const float* __restrict__ bk,
    const float* __restrict__ Wv, const float* __restrict__ bv,
    unsigned short* __restrict__ wp, float* __restrict__ bias)
{
    const int T    = blockIdx.x * 256 + threadIdx.x;   // 81920 threads
    const int j    = T & 7;
    const int lane = (T >> 3) & 63;
    const int ks   = (T >> 9) & 7;
    const int mt   = T >> 12;
    const int m = mt * 16 + (lane & 15);
    const int k = ks * 32 + ((lane >> 4) << 3) + j;
    float wv;
    if (m < 32)       wv = Wq[m * NC + k] * LOG2E;
    else if (m < 64)  wv = Wk[(m - 32) * NC + k];
    else              wv = Wv[(m - 64) * NC + k];
    wp[T] = f2bf(wv);
    if (T < NM) {
        float bb;
        if (T < 32)      bb = bq[T] * LOG2E;
        else if (T < 64) bb = bk[T - 32];
        else             bb = bv[T - 64];
        bias[T] = bb;
    }
}

// ---------------------------------------------------------------------------
// MFMA projection.  A = x (m = pixel), B = W^T.  K and V outputs written in
// MFMA-FRAGMENT-LINEAR layout (one contiguous 512B/1KB transaction per frag):
//   K: [b][jtile(256)][lane(64)][8]  lane = (d>>3)*16 + (j&15), elem d&7
//   V: [b][ctile(16)][jtile(256)][lane(64)][4] lane = ((j>>2)&3)*16 + (c&15)
// ---------------------------------------------------------------------------
__global__ __launch_bounds__(256, 4) void proj_kernel(
    const float* __restrict__ x,
    const unsigned short* __restrict__ wp,
    const float* __restrict__ bias,
    unsigned short* __restrict__ q_ws,
    unsigned short* __restrict__ k_ws,
    unsigned short* __restrict__ v_ws)
{
    __shared__ __align__(16) unsigned short xs[32 * XSTR];   // 16.9 KB

    const int b  = blockIdx.x >> 7;          // 128 tiles per batch
    const int n0 = (blockIdx.x & 127) << 5;
    const int t  = threadIdx.x;

    {
        const int n  = t & 31;
        const int cg = t >> 5;               // 0..7
        const float* xb = x + (size_t)b * NC * NN + n0 + n;
        #pragma unroll
        for (int it = 0; it < 8; ++it) {
            const int c = 32 * it + 4 * cg;
            const float x0 = xb[(size_t)(c + 0) * NN];
            const float x1 = xb[(size_t)(c + 1) * NN];
            const float x2 = xb[(size_t)(c + 2) * NN];
            const float x3 = xb[(size_t)(c + 3) * NN];
            uint2 pk;
            pk.x = (f2bf_u(x1) << 16) | f2bf_u(x0);
            pk.y = (f2bf_u(x3) << 16) | f2bf_u(x2);
            *(uint2*)(xs + n * XSTR + c) = pk;
        }
    }
    __syncthreads();

    const int w    = t >> 6;
    const int lane = t & 63;
    const int li = lane & 15;
    const int qd = lane >> 4;

    f32x4 acc[5][2];
    #pragma unroll
    for (int u = 0; u < 5; ++u) {
        const float bb = bias[(w + 4 * u) * 16 + li];
        acc[u][0] = (f32x4){bb, bb, bb, bb};
        acc[u][1] = (f32x4){bb, bb, bb, bb};
    }

    #pragma unroll
    for (int ks = 0; ks < 8; ++ks) {
        short8 af[2];
        #pragma unroll
        for (int mt = 0; mt < 2; ++mt)
            af[mt] = *(const short8*)(xs + (mt * 16 + li) * XSTR + ks * 32 + qd * 8);
        #pragma unroll
        for (int u = 0; u < 5; ++u) {
            const int ct = w + 4 * u;
            const short8 bf = *(const short8*)(wp + (size_t)((ct * 8 + ks) * 64 + lane) * 8);
            acc[u][0] = __builtin_amdgcn_mfma_f32_16x16x32_bf16(af[0], bf, acc[u][0], 0, 0, 0);
            acc[u][1] = __builtin_amdgcn_mfma_f32_16x16x32_bf16(af[1], bf, acc[u][1], 0, 0, 0);
        }
    }

    #pragma unroll
    for (int u = 0; u < 5; ++u) {
        const int ct = w + 4 * u;
        if (ct < 2) {
            // Q: row-major [b][n][d] (read once by attn; layout uncritical)
            const int d = ct * 16 + li;
            #pragma unroll
            for (int mt = 0; mt < 2; ++mt)
                #pragma unroll
                for (int r = 0; r < 4; ++r) {
                    const int n = n0 + mt * 16 + 4 * qd + r;
                    q_ws[((size_t)b * NN + n) * ND + d] = f2bf(acc[u][mt][r]);
                }
        } else if (ct < 4) {
            // K: fragment-linear
            const int d = (ct & 1) * 16 + li;
            #pragma unroll
            for (int mt = 0; mt < 2; ++mt)
                #pragma unroll
                for (int r = 0; r < 4; ++r) {
                    const int n = n0 + mt * 16 + 4 * qd + r;
                    k_ws[((size_t)(b * 256 + (n >> 4)) * 64 + (d >> 3) * 16 + (n & 15)) * 8 + (d & 7)]
                        = f2bf(acc[u][mt][r]);
                }
        } else {
            // V: fragment-linear; uint2 = V[cv][n..n+3] -> lane (qd*16+li), 4 elems
            const int ctv = ct - 4;              // V c-tile 0..15
            #pragma unroll
            for (int mt = 0; mt < 2; ++mt) {
                const int jt = (n0 >> 4) + mt;
                uint2 pk;
                pk.x = (f2bf_u(acc[u][mt][1]) << 16) | f2bf_u(acc[u][mt][0]);
                pk.y = (f2bf_u(acc[u][mt][3]) << 16) | f2bf_u(acc[u][mt][2]);
                *(uint2*)(v_ws + (((size_t)(b * 16 + ctv) * 256 + jt) * 64 + qd * 16 + li) * 4) = pk;
            }
        }
    }
}

// ---------------------------------------------------------------------------
// Flash attention R18 (third submit; R11/R12 benches were container-
// acquisition failures — kernel never ran): R12 VERBATIM STRUCTURE (the
// 154.7us best: barrier-free, LDS-free, fragment-linear K/V, 4 waves x
// {64 i-rows, 64 ch}, grid 512, 2 blocks/CU) + two pure ILP reorders
// targeting R12's ~960 stall cycles/SIMD/half:
//   1. S-phase batched x4: issue 4 independent S-MFMAs into s[4], THEN
//      their 16 exp2 + pack — MFMA->VALU latency hides under MFMA issue
//      (was: mfma, 4 dependent exp2 back-to-back, 8x per half).
//   2. PV jt-outer, sb-inner: accumulator o[sb][ct] dependency distance
//      2 -> 4 (was back-to-back dependent MFMA pairs on each acc).
// No decomposition change, no new loads, no new buffers (+16 transient
// VGPR for s[4]).  Ledger: R13/R16/R17 (work-split / occupancy variants)
// all regressed; R15 (in-wave interleave) regressed -> issue-port model:
// only instr count and dep stalls matter; these reorders cut stalls only.
// Fragment math identical to R12 (passed).
// ---------------------------------------------------------------------------
__global__ __launch_bounds__(256, 2) void attn_kernel(
    const unsigned short* __restrict__ q_ws,
    const unsigned short* __restrict__ k_ws,
    const unsigned short* __restrict__ v_ws,
    float* __restrict__ out)
{
    const int b  = blockIdx.x & 7;           // batch == XCD
    const int i0 = (blockIdx.x >> 3) * 64;
    const int w    = threadIdx.x >> 6;       // 0..3
    const int lane = threadIdx.x & 63;
    const int li = lane & 15;
    const int qd = lane >> 4;
    const int c0 = 64 * w;                   // channel slice (64 ch)

    // Q fragments for the 4 i-strips (B-operand of S-MFMA: col=i, k=d)
    short8 qf[4];
    #pragma unroll
    for (int sb = 0; sb < 4; ++sb)
        qf[sb] = *(const short8*)(q_ws + ((size_t)b * NN + i0 + 16 * sb + li) * ND + qd * 8);

    // Fragment-linear bases: K frag = 512 shorts, V frag = 256 shorts
    const unsigned short* kfb = k_ws + ((size_t)b * 256 * 64 + lane) * 8;
    const unsigned short* vtb[4];
    #pragma unroll
    for (int ct = 0; ct < 4; ++ct)
        vtb[ct] = v_ws + (((size_t)(b * 16 + (c0 >> 4) + ct) * 256) * 64 + lane) * 4;

    f32x4 o[4][4];                           // [i-strip][c-tile] (acc regs)
    #pragma unroll
    for (int sb = 0; sb < 4; ++sb)
        #pragma unroll
        for (int ct = 0; ct < 4; ++ct)
            o[sb][ct] = (f32x4){0.f, 0.f, 0.f, 0.f};
    float l_loc[4] = {0.f, 0.f, 0.f, 0.f};
    const f32x4 z4 = {0.f, 0.f, 0.f, 0.f};

    short8 kHA[2], kHB[2];                   // K frags, half-chunk, dbl-buf
    uint2  vs[4][2];                         // V slots: [ct][jt]
    uint2  pk[4][2];                         // packed P: [sb][jt]

    // One 32-j half-chunk at j0 (frag f0 = j0/16); kc current, kn next.
    auto HALF = [&](int j0, short8 (&kc)[2], short8 (&kn)[2]) {
        const size_t f0 = (size_t)(j0 >> 4);
        // next-half K at TOP (double-buffered, no WAR): max cover
        kn[0] = *(const short8*)(kfb + (f0 + 2) * 512);
        kn[1] = *(const short8*)(kfb + (f0 + 3) * 512);
        // V ct2/ct3 for THIS half: used after the S phase.
        vs[2][0] = *(const uint2*)(vtb[2] + (f0    ) * 256);
        vs[2][1] = *(const uint2*)(vtb[2] + (f0 + 1) * 256);
        vs[3][0] = *(const uint2*)(vtb[3] + (f0    ) * 256);
        vs[3][1] = *(const uint2*)(vtb[3] + (f0 + 1) * 256);
        // S phase: 2 batches of {4 independent MFMAs, then 16 exp2 + pack}
        #pragma unroll
        for (int sp = 0; sp < 2; ++sp) {     // strip pair: sb = 2sp, 2sp+1
            f32x4 s[4];
            s[0] = __builtin_amdgcn_mfma_f32_16x16x32_bf16(kc[0], qf[2 * sp    ], z4, 0, 0, 0);
            s[1] = __builtin_amdgcn_mfma_f32_16x16x32_bf16(kc[1], qf[2 * sp    ], z4, 0, 0, 0);
            s[2] = __builtin_amdgcn_mfma_f32_16x16x32_bf16(kc[0], qf[2 * sp + 1], z4, 0, 0, 0);
            s[3] = __builtin_amdgcn_mfma_f32_16x16x32_bf16(kc[1], qf[2 * sp + 1], z4, 0, 0, 0);
            #pragma unroll
            for (int u = 0; u < 4; ++u) {
                const int sb = 2 * sp + (u >> 1);
                const int jt = u & 1;
                const float p0 = __builtin_amdgcn_exp2f(s[u][0]);
                const float p1 = __builtin_amdgcn_exp2f(s[u][1]);
                const float p2 = __builtin_amdgcn_exp2f(s[u][2]);
                const float p3 = __builtin_amdgcn_exp2f(s[u][3]);
                l_loc[sb] += (p0 + p1) + (p2 + p3);
                const unsigned u0 = __float_as_uint(p0) + 0x8000u;
                const unsigned u1 = __float_as_uint(p1) + 0x8000u;
                const unsigned u2 = __float_as_uint(p2) + 0x8000u;
                const unsigned u3 = __float_as_uint(p3) + 0x8000u;
                pk[sb][jt].x = __builtin_amdgcn_perm(u1, u0, 0x07060302u);
                pk[sb][jt].y = __builtin_amdgcn_perm(u3, u2, 0x07060302u);
            }
        }
        // PV phase: 4 ct-groups; jt OUTER, sb inner (acc dep distance 4);
        // next-half ct0/ct1 loads between groups (unchanged from R12)
        #pragma unroll
        for (int ct = 0; ct < 4; ++ct) {
            #pragma unroll
            for (int jt = 0; jt < 2; ++jt)
                #pragma unroll
                for (int sb = 0; sb < 4; ++sb)
                    o[sb][ct] = __builtin_amdgcn_mfma_f32_16x16x16bf16_1k(
                        __builtin_bit_cast(short4v, vs[ct][jt]),
                        __builtin_bit_cast(short4v, pk[sb][jt]), o[sb][ct], 0, 0, 0);
            if (ct < 2) {   // reload this slot for the NEXT half
                vs[ct][0] = *(const uint2*)(vtb[ct] + (f0 + 2) * 256);
                vs[ct][1] = *(const uint2*)(vtb[ct] + (f0 + 3) * 256);
            }
        }
    };

    // ---- prologue: K(half 0) + V ct0/ct1(half 0) ----
    kHA[0] = *(const short8*)(kfb);
    kHA[1] = *(const short8*)(kfb + 512);
    #pragma unroll
    for (int ct = 0; ct < 2; ++ct) {
        vs[ct][0] = *(const uint2*)(vtb[ct]);
        vs[ct][1] = *(const uint2*)(vtb[ct] + 256);
    }

    // ---- main loop: 64 iterations x 2 half-chunks (tail prefetches read
    // harmlessly into adjacent d_ws regions; never consumed) ----
    #pragma unroll 1
    for (int t = 0; t < 64; ++t) {
        HALF(64 * t,      kHA, kHB);
        HALF(64 * t + 32, kHB, kHA);
    }

    // ---- l reduction: fully intra-wave (sum over qd groups) ----
    #pragma unroll
    for (int sb = 0; sb < 4; ++sb) {
        l_loc[sb] += __shfl_xor(l_loc[sb], 16, 64);
        l_loc[sb] += __shfl_xor(l_loc[sb], 32, 64);
    }

    #pragma unroll
    for (int sb = 0; sb < 4; ++sb) {
        const float linv = 1.0f / l_loc[sb];
        #pragma unroll
        for (int ct = 0; ct < 4; ++ct) {
            const int c = c0 + ct * 16 + qd * 4;
            float* op = out + ((size_t)b * NC + c) * NN + i0 + 16 * sb + li;
            #pragma unroll
            for (int r = 0; r < 4; ++r)
                op[(size_t)r * NN] = o[sb][ct][r] * linv;
        }
    }
}

// ---------------------------------------------------------------------------
extern "C" void kernel_launch(void* const* d_in, const int* in_sizes, int n_in,
                              void* d_out, int out_size, void* d_ws, size_t ws_size,
                              hipStream_t stream) {
    const float* x  = (const float*)d_in[0];
    const float* Wq = (const float*)d_in[1];
    const float* bq = (const float*)d_in[2];
    const float* Wk = (const float*)d_in[3];
    const float* bk = (const float*)d_in[4];
    const float* Wv = (const float*)d_in[5];
    const float* bv = (const float*)d_in[6];
    float* out = (float*)d_out;

    unsigned short* q_ws = (unsigned short*)d_ws;            // 2 MB
    unsigned short* k_ws = q_ws + (size_t)NB * NN * ND;      // 2 MB
    unsigned short* v_ws = k_ws + (size_t)NB * NN * ND;      // 16 MB
    unsigned short* wp   = v_ws + (size_t)NB * NC * NN;      // 160 KB
    float*          bias = (float*)(wp + (size_t)NM * NC);   // 1.25 KB

    repack_kernel<<<NM * NC / 256, 256, 0, stream>>>(Wq, bq, Wk, bk, Wv, bv, wp, bias);
    proj_kernel<<<NB * (NN / 32), 256, 0, stream>>>(x, wp, bias, q_ws, k_ws, v_ws);
    attn_kernel<<<NB * (NN / 64), 256, 0, stream>>>(q_ws, k_ws, v_ws, out);
}